// Round 1
// baseline (1337.485 us; speedup 1.0000x reference)
//
#include <hip/hip_runtime.h>
#include <math.h>

#define MI 512
#define NPT 8192
#define JIT 1e-6f
#define LOG2PI 1.8378770664093453f

// ws float offsets
#define OFF_A    0         // 512x512 Kuu -> L (lower)
#define OFF_LINV 262144    // 512x512 L^-1 (upper zero-filled)
#define OFF_QS   524288    // 512x512 q_sqrt
#define OFF_QC   786432    // 512x512 q_cov
#define OFF_DINV 1048576   // 8 x 64x64 diag-block inverses
#define OFF_W    1081344   // 512  w = Linv^T q_mu
#define OFF_PART 1081856   // 512 block partial ell sums

#define FMA16(ACC,a0,a1,a2,a3,b0,b1,b2,b3) \
  ACC[0][0]+=a0*b0; ACC[0][1]+=a0*b1; ACC[0][2]+=a0*b2; ACC[0][3]+=a0*b3; \
  ACC[1][0]+=a1*b0; ACC[1][1]+=a1*b1; ACC[1][2]+=a1*b2; ACC[1][3]+=a1*b3; \
  ACC[2][0]+=a2*b0; ACC[2][1]+=a2*b1; ACC[2][2]+=a2*b2; ACC[2][3]+=a2*b3; \
  ACC[3][0]+=a3*b0; ACC[3][1]+=a3*b1; ACC[3][2]+=a3*b2; ACC[3][3]+=a3*b3;

// ---------------------------------------------------------------- prep
__global__ __launch_bounds__(256) void k_prep(const float* __restrict__ Z,
    const float* __restrict__ qlv, const float* __restrict__ lsP,
    const float* __restrict__ osP, float* __restrict__ ws) {
  int u = blockIdx.x*256 + threadIdx.x;
  float ls = lsP[0], os = osP[0];
  float ils2 = 1.0f/(ls*ls);
  if (u < MI*MI) {
    int i = u >> 9, j = u & 511;
    float4 a0 = *(const float4*)(Z + i*8);
    float4 a1 = *(const float4*)(Z + i*8 + 4);
    float4 b0 = *(const float4*)(Z + j*8);
    float4 b1 = *(const float4*)(Z + j*8 + 4);
    float d0=a0.x-b0.x, d1=a0.y-b0.y, d2=a0.z-b0.z, d3=a0.w-b0.w;
    float d4=a1.x-b1.x, d5=a1.y-b1.y, d6=a1.z-b1.z, d7=a1.w-b1.w;
    float sq = d0*d0+d1*d1+d2*d2+d3*d3+d4*d4+d5*d5+d6*d6+d7*d7;
    float v = os*__expf(-0.5f*ils2*sq);
    if (i==j) v += JIT;
    ws[OFF_A + u] = v;
  } else {
    int w2 = u - MI*MI;
    if (w2 < MI*MI) {
      int i = w2 >> 9, j = w2 & 511;
      ws[OFF_QS + w2] = (j <= i) ? __expf(0.5f*qlv[w2]) : 0.0f;
    }
  }
}

// ------------------------------------------------- O = X Y^T + adiag*I (K=512)
__global__ __launch_bounds__(256) void k_gemm_nt(const float* __restrict__ X,
    const float* __restrict__ Y, float* __restrict__ O, float adiag) {
  __shared__ float Xs[64][20], Ys[64][20];
  int tid = threadIdx.x;
  int bi = blockIdx.y, bj = blockIdx.x;
  int ty4 = (tid >> 4)*4, tx4 = (tid & 15)*4;
  int lrow = tid >> 2, lc4 = (tid & 3)*4;
  float acc[4][4] = {{0.f}};
  for (int kc = 0; kc < 512; kc += 16) {
    float4 xa = *(const float4*)(X + (bi*64+lrow)*512 + kc + lc4);
    float4 ya = *(const float4*)(Y + (bj*64+lrow)*512 + kc + lc4);
    Xs[lrow][lc4+0]=xa.x; Xs[lrow][lc4+1]=xa.y; Xs[lrow][lc4+2]=xa.z; Xs[lrow][lc4+3]=xa.w;
    Ys[lrow][lc4+0]=ya.x; Ys[lrow][lc4+1]=ya.y; Ys[lrow][lc4+2]=ya.z; Ys[lrow][lc4+3]=ya.w;
    __syncthreads();
    #pragma unroll
    for (int kk = 0; kk < 16; ++kk) {
      float a0=Xs[ty4+0][kk],a1=Xs[ty4+1][kk],a2=Xs[ty4+2][kk],a3=Xs[ty4+3][kk];
      float b0=Ys[tx4+0][kk],b1=Ys[tx4+1][kk],b2=Ys[tx4+2][kk],b3=Ys[tx4+3][kk];
      FMA16(acc,a0,a1,a2,a3,b0,b1,b2,b3)
    }
    __syncthreads();
  }
  #pragma unroll
  for (int u = 0; u < 4; ++u)
    #pragma unroll
    for (int v = 0; v < 4; ++v) {
      int gi = bi*64+ty4+u, gj = bj*64+tx4+v;
      float o = acc[u][v]; if (gi==gj) o += adiag;
      O[gi*512+gj] = o;
    }
}

// ------------------------- per-panel: Gram update + factor + invert diag block
__global__ __launch_bounds__(256) void k_chol_diag(float* __restrict__ ws, int p) {
  float* A = ws + OFF_A;
  float* DINV = ws + OFF_DINV;
  __shared__ float Ds[64][65];
  __shared__ float Lk[64][20];
  __shared__ float Vs[64][65];
  __shared__ float red[64][5];
  int tid = threadIdx.x;
  int ty4 = (tid >> 4)*4, tx4 = (tid & 15)*4;
  int lrow = tid >> 2, lc4 = (tid & 3)*4;
  int base = p*64;
  float acc[4][4] = {{0.f}};
  for (int kc = 0; kc < base; kc += 16) {
    float4 la = *(const float4*)(A + (base+lrow)*512 + kc + lc4);
    Lk[lrow][lc4+0]=la.x; Lk[lrow][lc4+1]=la.y; Lk[lrow][lc4+2]=la.z; Lk[lrow][lc4+3]=la.w;
    __syncthreads();
    #pragma unroll
    for (int kk = 0; kk < 16; ++kk) {
      float a0=Lk[ty4+0][kk],a1=Lk[ty4+1][kk],a2=Lk[ty4+2][kk],a3=Lk[ty4+3][kk];
      float b0=Lk[tx4+0][kk],b1=Lk[tx4+1][kk],b2=Lk[tx4+2][kk],b3=Lk[tx4+3][kk];
      FMA16(acc,a0,a1,a2,a3,b0,b1,b2,b3)
    }
    __syncthreads();
  }
  #pragma unroll
  for (int u = 0; u < 4; ++u)
    #pragma unroll
    for (int v = 0; v < 4; ++v)
      Ds[ty4+u][tx4+v] = A[(base+ty4+u)*512 + base+tx4+v] - acc[u][v];
  __syncthreads();
  // in-LDS right-looking Cholesky of 64x64
  for (int j = 0; j < 64; ++j) {
    float s = Ds[j][j];
    float Ljj = sqrtf(s);
    float rinv = 1.0f/Ljj;
    __syncthreads();
    if (tid == 0) Ds[j][j] = Ljj;
    if (tid > j && tid < 64) Ds[tid][j] *= rinv;
    __syncthreads();
    int i = tid >> 2, ko = tid & 3;
    if (i > j) {
      float lij = Ds[i][j];
      for (int k = j+1+ko; k <= i; k += 4) Ds[i][k] -= lij*Ds[k][j];
    }
    __syncthreads();
  }
  // in-LDS inverse of the lower-tri factor
  for (int e = tid; e < 4096; e += 256) Vs[e>>6][e&63] = 0.0f;
  __syncthreads();
  int c = tid & 63, q = tid >> 6;
  for (int j = 0; j < 64; ++j) {
    float partial = 0.f;
    if (j > c) for (int k = c+q; k < j; k += 4) partial += Ds[j][k]*Vs[k][c];
    red[c][q] = partial;
    __syncthreads();
    if (q == 0 && j >= c) {
      float sum = red[c][0]+red[c][1]+red[c][2]+red[c][3];
      Vs[j][c] = (((j==c)?1.0f:0.0f) - sum) / Ds[j][j];
    }
    __syncthreads();
  }
  for (int e = tid; e < 4096; e += 256) {
    int i = e >> 6, jj = e & 63;
    if (jj <= i) A[(base+i)*512 + base + jj] = Ds[i][jj];
    DINV[p*4096 + e] = Vs[i][jj];
  }
}

// --------------------- sub-panel: Lsub = (A - sum L L^T) * Dinv^T
__global__ __launch_bounds__(256) void k_chol_sub(float* __restrict__ ws, int p) {
  float* A = ws + OFF_A;
  float* DINV = ws + OFF_DINV;
  __shared__ float LkR[64][20], LkC[64][20];
  __shared__ float T[64][65];
  __shared__ float Dv[64][65];
  int tid = threadIdx.x;
  int ty4 = (tid >> 4)*4, tx4 = (tid & 15)*4;
  int lrow = tid >> 2, lc4 = (tid & 3)*4;
  int base = p*64;
  int R = 64*(p+1+blockIdx.x);
  float acc[4][4] = {{0.f}};
  for (int kc = 0; kc < base; kc += 16) {
    float4 ra = *(const float4*)(A + (R+lrow)*512 + kc + lc4);
    float4 ca = *(const float4*)(A + (base+lrow)*512 + kc + lc4);
    LkR[lrow][lc4+0]=ra.x; LkR[lrow][lc4+1]=ra.y; LkR[lrow][lc4+2]=ra.z; LkR[lrow][lc4+3]=ra.w;
    LkC[lrow][lc4+0]=ca.x; LkC[lrow][lc4+1]=ca.y; LkC[lrow][lc4+2]=ca.z; LkC[lrow][lc4+3]=ca.w;
    __syncthreads();
    #pragma unroll
    for (int kk = 0; kk < 16; ++kk) {
      float a0=LkR[ty4+0][kk],a1=LkR[ty4+1][kk],a2=LkR[ty4+2][kk],a3=LkR[ty4+3][kk];
      float b0=LkC[tx4+0][kk],b1=LkC[tx4+1][kk],b2=LkC[tx4+2][kk],b3=LkC[tx4+3][kk];
      FMA16(acc,a0,a1,a2,a3,b0,b1,b2,b3)
    }
    __syncthreads();
  }
  #pragma unroll
  for (int u = 0; u < 4; ++u)
    #pragma unroll
    for (int v = 0; v < 4; ++v)
      T[ty4+u][tx4+v] = A[(R+ty4+u)*512 + base+tx4+v] - acc[u][v];
  for (int e = tid; e < 4096; e += 256) Dv[e>>6][e&63] = DINV[p*4096 + e];
  __syncthreads();
  float acc2[4][4] = {{0.f}};
  for (int t2 = 0; t2 < 64; ++t2) {
    float a0=T[ty4+0][t2],a1=T[ty4+1][t2],a2=T[ty4+2][t2],a3=T[ty4+3][t2];
    float b0=Dv[tx4+0][t2],b1=Dv[tx4+1][t2],b2=Dv[tx4+2][t2],b3=Dv[tx4+3][t2];
    FMA16(acc2,a0,a1,a2,a3,b0,b1,b2,b3)
  }
  #pragma unroll
  for (int u = 0; u < 4; ++u)
    #pragma unroll
    for (int v = 0; v < 4; ++v)
      A[(R+ty4+u)*512 + base+tx4+v] = acc2[u][v];
}

// --------------------- Linv block-row s: forward substitution with Dinv
__global__ __launch_bounds__(256) void k_trsm_fwd(float* __restrict__ ws, int s) {
  float* A = ws + OFF_A;
  float* LINV = ws + OFF_LINV;
  float* DINV = ws + OFF_DINV;
  int tid = threadIdx.x;
  int J = blockIdx.x;
  if (J > s) {
    for (int e = tid; e < 4096; e += 256)
      LINV[(64*s + (e>>6))*512 + 64*J + (e&63)] = 0.0f;
    return;
  }
  if (J == s) {
    for (int e = tid; e < 4096; e += 256)
      LINV[(64*s + (e>>6))*512 + 64*s + (e&63)] = DINV[s*4096 + e];
    return;
  }
  __shared__ float Lt[64][20];
  __shared__ float Xt[16][68];
  __shared__ float T[64][65];
  __shared__ float Dv[64][65];
  int ty4 = (tid >> 4)*4, tx4 = (tid & 15)*4;
  int lrow = tid >> 2, lc4 = (tid & 3)*4;
  int trow = tid >> 4, tj4 = (tid & 15)*4;
  float acc[4][4] = {{0.f}};
  for (int k = J; k < s; ++k) {
    for (int tc = 0; tc < 64; tc += 16) {
      float4 la = *(const float4*)(A + (64*s+lrow)*512 + 64*k + tc + lc4);
      Lt[lrow][lc4+0]=la.x; Lt[lrow][lc4+1]=la.y; Lt[lrow][lc4+2]=la.z; Lt[lrow][lc4+3]=la.w;
      float4 xa = *(const float4*)(LINV + (64*k+tc+trow)*512 + 64*J + tj4);
      Xt[trow][tj4+0]=xa.x; Xt[trow][tj4+1]=xa.y; Xt[trow][tj4+2]=xa.z; Xt[trow][tj4+3]=xa.w;
      __syncthreads();
      #pragma unroll
      for (int tt = 0; tt < 16; ++tt) {
        float a0=Lt[ty4+0][tt],a1=Lt[ty4+1][tt],a2=Lt[ty4+2][tt],a3=Lt[ty4+3][tt];
        float b0=Xt[tt][tx4+0],b1=Xt[tt][tx4+1],b2=Xt[tt][tx4+2],b3=Xt[tt][tx4+3];
        FMA16(acc,a0,a1,a2,a3,b0,b1,b2,b3)
      }
      __syncthreads();
    }
  }
  #pragma unroll
  for (int u = 0; u < 4; ++u)
    #pragma unroll
    for (int v = 0; v < 4; ++v)
      T[ty4+u][tx4+v] = acc[u][v];
  for (int e = tid; e < 4096; e += 256) Dv[e>>6][e&63] = DINV[s*4096 + e];
  __syncthreads();
  float acc2[4][4] = {{0.f}};
  for (int t2 = 0; t2 < 64; ++t2) {
    float a0=Dv[ty4+0][t2],a1=Dv[ty4+1][t2],a2=Dv[ty4+2][t2],a3=Dv[ty4+3][t2];
    float b0=T[t2][tx4+0],b1=T[t2][tx4+1],b2=T[t2][tx4+2],b3=T[t2][tx4+3];
    FMA16(acc2,a0,a1,a2,a3,b0,b1,b2,b3)
  }
  #pragma unroll
  for (int u = 0; u < 4; ++u)
    #pragma unroll
    for (int v = 0; v < 4; ++v)
      LINV[(64*s+ty4+u)*512 + 64*J+tx4+v] = -acc2[u][v];
}

// --------------------- w = Linv^T q_mu
__global__ __launch_bounds__(256) void k_wvec(const float* __restrict__ qmu,
                                              float* __restrict__ ws) {
  const float* LINV = ws + OFF_LINV;
  float* W = ws + OFF_W;
  int c = blockIdx.x*256 + threadIdx.x;
  float acc = 0.f;
  for (int r = 0; r < 512; ++r) acc += LINV[r*512 + c]*qmu[r];
  W[c] = acc;
}

// --------------------- main: per-point quadratic forms + ell partials
#define MAIN_CHUNK(SRC, ACC) { \
  const float* _s = (SRC); \
  float4 v0=*(const float4*)(_s); float4 v1=*(const float4*)(_s+4); \
  float4 v2=*(const float4*)(_s+8); float4 v3=*(const float4*)(_s+12); \
  ST[0*260+tid]=v0.x;  ST[1*260+tid]=v0.y;  ST[2*260+tid]=v0.z;  ST[3*260+tid]=v0.w; \
  ST[4*260+tid]=v1.x;  ST[5*260+tid]=v1.y;  ST[6*260+tid]=v1.z;  ST[7*260+tid]=v1.w; \
  ST[8*260+tid]=v2.x;  ST[9*260+tid]=v2.y;  ST[10*260+tid]=v2.z; ST[11*260+tid]=v2.w; \
  ST[12*260+tid]=v3.x; ST[13*260+tid]=v3.y; ST[14*260+tid]=v3.z; ST[15*260+tid]=v3.w; \
  __syncthreads(); \
  _Pragma("unroll") \
  for (int cc = 0; cc < 16; ++cc) { \
    float4 kv = *(const float4*)&KL[(c0+cc)*16 + pq4]; \
    float4 lv = *(const float4*)&ST[cc*260 + rq4]; \
    FMA16(ACC, lv.x, lv.y, lv.z, lv.w, kv.x, kv.y, kv.z, kv.w) \
  } \
  __syncthreads(); }

__global__ __launch_bounds__(256) void k_main(const float* __restrict__ X,
    const float* __restrict__ Yv, const float* __restrict__ Z,
    const float* __restrict__ llvP, const float* __restrict__ lsP,
    const float* __restrict__ osP, float* __restrict__ ws) {
  const float* LINV = ws + OFF_LINV;
  const float* QC = ws + OFF_QC;
  const float* W = ws + OFF_W;
  float* PART = ws + OFF_PART;
  __shared__ float KL[8192];      // 512 x 16 : k tile, then l tile
  __shared__ float ST[4160];      // 16 x 260 stage / reduction scratch
  __shared__ float wsh[512];
  __shared__ float Xs[16][8];
  __shared__ float pmv[16], lsqv[16], elli[16];
  int tid = threadIdx.x, B = blockIdx.x;
  float ls = lsP[0], os = osP[0], llv = llvP[0];
  float ils2 = 1.0f/(ls*ls);
  if (tid < 128) { int pp = tid>>3, d = tid&7; Xs[pp][d] = X[(B*16+pp)*8 + d]; }
  wsh[tid] = W[tid]; wsh[tid+256] = W[tid+256];
  __syncthreads();
  for (int e = tid; e < 8192; e += 256) {
    int cc = e >> 4, pp = e & 15;
    float4 z0 = *(const float4*)(Z + cc*8);
    float4 z1 = *(const float4*)(Z + cc*8 + 4);
    float d0=z0.x-Xs[pp][0], d1=z0.y-Xs[pp][1], d2=z0.z-Xs[pp][2], d3=z0.w-Xs[pp][3];
    float d4=z1.x-Xs[pp][4], d5=z1.y-Xs[pp][5], d6=z1.z-Xs[pp][6], d7=z1.w-Xs[pp][7];
    float sq = d0*d0+d1*d1+d2*d2+d3*d3+d4*d4+d5*d5+d6*d6+d7*d7;
    KL[e] = os*__expf(-0.5f*ils2*sq);
  }
  __syncthreads();
  int rq = tid >> 2;
  int rq4 = rq*4, pq4 = (tid & 3)*4;
  // phase A: l = Linv @ k  (slab0 rows 0..255 skip upper chunks; slab1 full)
  float acc0[4][4] = {{0.f}}, acc1[4][4] = {{0.f}};
  for (int ch = 0; ch < 16; ++ch) { int c0 = ch*16; MAIN_CHUNK(LINV + tid*512 + c0, acc0) }
  for (int ch = 0; ch < 32; ++ch) { int c0 = ch*16; MAIN_CHUNK(LINV + (256+tid)*512 + c0, acc1) }
  // pred-mean partials (KL still holds k) and ||l||^2 partials
  float pmp[4] = {0.f,0.f,0.f,0.f};
  for (int c8 = 0; c8 < 8; ++c8) {
    int cc2 = rq*8 + c8;
    float wv = wsh[cc2];
    pmp[0] += KL[cc2*16+pq4+0]*wv; pmp[1] += KL[cc2*16+pq4+1]*wv;
    pmp[2] += KL[cc2*16+pq4+2]*wv; pmp[3] += KL[cc2*16+pq4+3]*wv;
  }
  float lsp[4] = {0.f,0.f,0.f,0.f};
  #pragma unroll
  for (int u = 0; u < 4; ++u)
    #pragma unroll
    for (int v = 0; v < 4; ++v)
      lsp[v] += acc0[u][v]*acc0[u][v] + acc1[u][v]*acc1[u][v];
  #pragma unroll
  for (int v = 0; v < 4; ++v) {
    ST[rq*17 + pq4+v] = pmp[v];
    ST[1088 + rq*17 + pq4+v] = lsp[v];
  }
  __syncthreads();
  if (tid < 16) {
    float a = 0.f, b = 0.f;
    for (int r2 = 0; r2 < 64; ++r2) { a += ST[r2*17+tid]; b += ST[1088+r2*17+tid]; }
    pmv[tid] = a; lsqv[tid] = b;
  }
  __syncthreads();
  // overwrite KL with l
  #pragma unroll
  for (int u = 0; u < 4; ++u) {
    *(float4*)&KL[(rq4+u)*16 + pq4] = make_float4(acc0[u][0],acc0[u][1],acc0[u][2],acc0[u][3]);
    *(float4*)&KL[(256+rq4+u)*16 + pq4] = make_float4(acc1[u][0],acc1[u][1],acc1[u][2],acc1[u][3]);
  }
  __syncthreads();
  // phase B: u = QC @ l, accumulate ||u||^2
  float usq[4] = {0.f,0.f,0.f,0.f};
  {
    float ua[4][4] = {{0.f}};
    for (int ch = 0; ch < 32; ++ch) { int c0 = ch*16; MAIN_CHUNK(QC + tid*512 + c0, ua) }
    #pragma unroll
    for (int u = 0; u < 4; ++u)
      #pragma unroll
      for (int v = 0; v < 4; ++v) usq[v] += ua[u][v]*ua[u][v];
  }
  {
    float ua[4][4] = {{0.f}};
    for (int ch = 0; ch < 32; ++ch) { int c0 = ch*16; MAIN_CHUNK(QC + (256+tid)*512 + c0, ua) }
    #pragma unroll
    for (int u = 0; u < 4; ++u)
      #pragma unroll
      for (int v = 0; v < 4; ++v) usq[v] += ua[u][v]*ua[u][v];
  }
  #pragma unroll
  for (int v = 0; v < 4; ++v) ST[rq*17 + pq4+v] = usq[v];
  __syncthreads();
  if (tid < 16) {
    float us = 0.f;
    for (int r2 = 0; r2 < 64; ++r2) us += ST[r2*17+tid];
    int gi = B*16 + tid;
    float diff = Yv[gi] - pmv[tid];
    float diagc = os + us - lsqv[tid];
    float iss = __expf(-llv);
    elli[tid] = -0.5f*((diff*diff + diagc)*iss + (LOG2PI + llv));
  }
  __syncthreads();
  if (tid == 0) {
    float s = 0.f;
    #pragma unroll
    for (int i2 = 0; i2 < 16; ++i2) s += elli[i2];
    PART[B] = s;
  }
}

// --------------------- final scalar
__global__ __launch_bounds__(256) void k_final(const float* __restrict__ qmu,
    const float* __restrict__ qlv, float* __restrict__ ws, float* __restrict__ out) {
  __shared__ double sh[256];
  int tid = threadIdx.x;
  const float* QC = ws + OFF_QC;
  const float* PART = ws + OFF_PART;
  double pa = 0.0, tr = 0.0, mm = 0.0, ld = 0.0;
  for (int i = tid; i < 512; i += 256) {
    pa += (double)PART[i];
    tr += (double)QC[i*513];
    double q = (double)qmu[i]; mm += q*q;
    ld += (double)qlv[i*513];
  }
  double vals[4] = {pa, tr, mm, ld};
  double res[4];
  for (int t2 = 0; t2 < 4; ++t2) {
    sh[tid] = vals[t2]; __syncthreads();
    for (int s2 = 128; s2 > 0; s2 >>= 1) {
      if (tid < s2) sh[tid] += sh[tid+s2];
      __syncthreads();
    }
    res[t2] = sh[0]; __syncthreads();
  }
  if (tid == 0) {
    double n = 8192.0;
    double ell = res[0]/n;
    double kl = 0.5*(res[1] + res[2] - 512.0 - res[3])/n;
    out[0] = (float)(ell - kl);
  }
}

extern "C" void kernel_launch(void* const* d_in, const int* in_sizes, int n_in,
                              void* d_out, int out_size, void* d_ws, size_t ws_size,
                              hipStream_t stream) {
  (void)in_sizes; (void)n_in; (void)out_size; (void)ws_size;
  const float* X   = (const float*)d_in[0];
  const float* Y   = (const float*)d_in[1];
  const float* Z   = (const float*)d_in[2];
  const float* qmu = (const float*)d_in[3];
  const float* qlv = (const float*)d_in[4];
  const float* llv = (const float*)d_in[5];
  const float* ls  = (const float*)d_in[6];
  const float* os  = (const float*)d_in[7];
  float* ws = (float*)d_ws;
  float* out = (float*)d_out;

  k_prep<<<2048, 256, 0, stream>>>(Z, qlv, ls, os, ws);
  k_gemm_nt<<<dim3(8,8), 256, 0, stream>>>(ws+OFF_QS, ws+OFF_QS, ws+OFF_QC, JIT);
  for (int p = 0; p < 8; ++p) {
    k_chol_diag<<<1, 256, 0, stream>>>(ws, p);
    if (p < 7) k_chol_sub<<<7-p, 256, 0, stream>>>(ws, p);
  }
  for (int s = 0; s < 8; ++s)
    k_trsm_fwd<<<8, 256, 0, stream>>>(ws, s);
  k_wvec<<<2, 256, 0, stream>>>(qmu, ws);
  k_main<<<512, 256, 0, stream>>>(X, Y, Z, llv, ls, os, ws);
  k_final<<<1, 256, 0, stream>>>(qmu, qlv, ws, out);
}

// Round 2
// 1202.704 us; speedup vs baseline: 1.1121x; 1.1121x over previous
//
#include <hip/hip_runtime.h>
#include <math.h>

#define MI 512
#define NPT 8192
#define JIT 1e-6f
#define LOG2PI 1.8378770664093453f

// ws float offsets
#define OFF_A     0         // 512x512 Kuu -> L (lower)
#define OFF_LINV  262144    // 512x512 Linv^T (LT[r][c] = Linv[c][r])
#define OFF_QS    524288    // 512x512 q_sqrt
#define OFF_QC    786432    // 512x512 q_cov (symmetric)
#define OFF_DINV  1048576   // 8 x 64x64 diag-block inverses
#define OFF_W     1081344   // 512  w = Linv^T q_mu
#define OFF_PART  1081856   // 512 block partial ell sums
#define OFF_FLAGS 1082368   // 8 chol flags + 64 linv flags (unsigned)

#define FMA16(ACC,a0,a1,a2,a3,b0,b1,b2,b3) \
  ACC[0][0]+=a0*b0; ACC[0][1]+=a0*b1; ACC[0][2]+=a0*b2; ACC[0][3]+=a0*b3; \
  ACC[1][0]+=a1*b0; ACC[1][1]+=a1*b1; ACC[1][2]+=a1*b2; ACC[1][3]+=a1*b3; \
  ACC[2][0]+=a2*b0; ACC[2][1]+=a2*b1; ACC[2][2]+=a2*b2; ACC[2][3]+=a2*b3; \
  ACC[3][0]+=a3*b0; ACC[3][1]+=a3*b1; ACC[3][2]+=a3*b2; ACC[3][3]+=a3*b3;

__device__ __forceinline__ void wait_flag(unsigned* f, int tid) {
  if (tid == 0) {
    while (__hip_atomic_load(f, __ATOMIC_RELAXED, __HIP_MEMORY_SCOPE_AGENT) == 0)
      __builtin_amdgcn_s_sleep(2);
    __builtin_amdgcn_fence(__ATOMIC_ACQUIRE, "agent");
  }
  __syncthreads();
}
__device__ __forceinline__ void raise_flag(unsigned* f, int tid) {
  __syncthreads();
  if (tid == 0) {
    __builtin_amdgcn_fence(__ATOMIC_RELEASE, "agent");
    __hip_atomic_store(f, 1u, __ATOMIC_RELAXED, __HIP_MEMORY_SCOPE_AGENT);
  }
}

// ---------------------------------------------------------------- prep
__global__ __launch_bounds__(256) void k_prep(const float* __restrict__ Z,
    const float* __restrict__ qlv, const float* __restrict__ lsP,
    const float* __restrict__ osP, float* __restrict__ ws) {
  int u = blockIdx.x*256 + threadIdx.x;
  if (blockIdx.x == 0 && threadIdx.x < 128)
    ((unsigned*)(ws + OFF_FLAGS))[threadIdx.x] = 0u;
  float ls = lsP[0], os = osP[0];
  float ils2 = 1.0f/(ls*ls);
  if (u < MI*MI) {
    int i = u >> 9, j = u & 511;
    float4 a0 = *(const float4*)(Z + i*8);
    float4 a1 = *(const float4*)(Z + i*8 + 4);
    float4 b0 = *(const float4*)(Z + j*8);
    float4 b1 = *(const float4*)(Z + j*8 + 4);
    float d0=a0.x-b0.x, d1=a0.y-b0.y, d2=a0.z-b0.z, d3=a0.w-b0.w;
    float d4=a1.x-b1.x, d5=a1.y-b1.y, d6=a1.z-b1.z, d7=a1.w-b1.w;
    float sq = d0*d0+d1*d1+d2*d2+d3*d3+d4*d4+d5*d5+d6*d6+d7*d7;
    float v = os*__expf(-0.5f*ils2*sq);
    if (i==j) v += JIT;
    ws[OFF_A + u] = v;
  } else {
    int w2 = u - MI*MI;
    if (w2 < MI*MI) {
      int i = w2 >> 9, j = w2 & 511;
      ws[OFF_QS + w2] = (j <= i) ? __expf(0.5f*qlv[w2]) : 0.0f;
    }
  }
}

// ------------------------------------------------- O = X Y^T + adiag*I (K=512)
__global__ __launch_bounds__(256) void k_gemm_nt(const float* __restrict__ X,
    const float* __restrict__ Y, float* __restrict__ O, float adiag) {
  __shared__ float Xs[64][20], Ys[64][20];
  int tid = threadIdx.x;
  int bi = blockIdx.y, bj = blockIdx.x;
  int ty4 = (tid >> 4)*4, tx4 = (tid & 15)*4;
  int lrow = tid >> 2, lc4 = (tid & 3)*4;
  float acc[4][4] = {{0.f}};
  for (int kc = 0; kc < 512; kc += 16) {
    float4 xa = *(const float4*)(X + (bi*64+lrow)*512 + kc + lc4);
    float4 ya = *(const float4*)(Y + (bj*64+lrow)*512 + kc + lc4);
    Xs[lrow][lc4+0]=xa.x; Xs[lrow][lc4+1]=xa.y; Xs[lrow][lc4+2]=xa.z; Xs[lrow][lc4+3]=xa.w;
    Ys[lrow][lc4+0]=ya.x; Ys[lrow][lc4+1]=ya.y; Ys[lrow][lc4+2]=ya.z; Ys[lrow][lc4+3]=ya.w;
    __syncthreads();
    #pragma unroll
    for (int kk = 0; kk < 16; ++kk) {
      float a0=Xs[ty4+0][kk],a1=Xs[ty4+1][kk],a2=Xs[ty4+2][kk],a3=Xs[ty4+3][kk];
      float b0=Ys[tx4+0][kk],b1=Ys[tx4+1][kk],b2=Ys[tx4+2][kk],b3=Ys[tx4+3][kk];
      FMA16(acc,a0,a1,a2,a3,b0,b1,b2,b3)
    }
    __syncthreads();
  }
  #pragma unroll
  for (int u = 0; u < 4; ++u)
    #pragma unroll
    for (int v = 0; v < 4; ++v) {
      int gi = bi*64+ty4+u, gj = bj*64+tx4+v;
      float o = acc[u][v]; if (gi==gj) o += adiag;
      O[gi*512+gj] = o;
    }
}

// ------------- fused Cholesky: block b owns row-block b; flags per panel
__global__ __launch_bounds__(256) void k_chol_all(float* __restrict__ ws) {
  float* A = ws + OFF_A;
  float* DINV = ws + OFF_DINV;
  unsigned* flg = (unsigned*)(ws + OFF_FLAGS);
  __shared__ float LkR[64][20], LkC[64][20];
  __shared__ float Ds[64][65];
  __shared__ float Vs[64][65];
  __shared__ float red[64][5];
  int tid = threadIdx.x, b = blockIdx.x;
  int ty4 = (tid >> 4)*4, tx4 = (tid & 15)*4;
  int lrow = tid >> 2, lc4 = (tid & 3)*4;
  int Rb = b*64;

  // ---- sub-panel columns p = 0..b-1 (left-looking)
  for (int p = 0; p < b; ++p) {
    int base = p*64;
    wait_flag(&flg[p], tid);
    float acc[4][4] = {{0.f}};
    for (int kc = 0; kc < base; kc += 16) {
      float4 ra = *(const float4*)(A + (Rb+lrow)*512 + kc + lc4);
      float4 ca = *(const float4*)(A + (base+lrow)*512 + kc + lc4);
      LkR[lrow][lc4+0]=ra.x; LkR[lrow][lc4+1]=ra.y; LkR[lrow][lc4+2]=ra.z; LkR[lrow][lc4+3]=ra.w;
      LkC[lrow][lc4+0]=ca.x; LkC[lrow][lc4+1]=ca.y; LkC[lrow][lc4+2]=ca.z; LkC[lrow][lc4+3]=ca.w;
      __syncthreads();
      #pragma unroll
      for (int kk = 0; kk < 16; ++kk) {
        float a0=LkR[ty4+0][kk],a1=LkR[ty4+1][kk],a2=LkR[ty4+2][kk],a3=LkR[ty4+3][kk];
        float b0=LkC[tx4+0][kk],b1=LkC[tx4+1][kk],b2=LkC[tx4+2][kk],b3=LkC[tx4+3][kk];
        FMA16(acc,a0,a1,a2,a3,b0,b1,b2,b3)
      }
      __syncthreads();
    }
    #pragma unroll
    for (int u = 0; u < 4; ++u)
      #pragma unroll
      for (int v = 0; v < 4; ++v)
        Ds[ty4+u][tx4+v] = A[(Rb+ty4+u)*512 + base+tx4+v] - acc[u][v];
    for (int e = tid; e < 4096; e += 256) Vs[e>>6][e&63] = DINV[p*4096 + e];
    __syncthreads();
    float acc2[4][4] = {{0.f}};
    for (int m = 0; m < 64; ++m) {
      float a0=Ds[ty4+0][m],a1=Ds[ty4+1][m],a2=Ds[ty4+2][m],a3=Ds[ty4+3][m];
      float b0=Vs[tx4+0][m],b1=Vs[tx4+1][m],b2=Vs[tx4+2][m],b3=Vs[tx4+3][m];
      FMA16(acc2,a0,a1,a2,a3,b0,b1,b2,b3)
    }
    #pragma unroll
    for (int u = 0; u < 4; ++u)
      #pragma unroll
      for (int v = 0; v < 4; ++v)
        A[(Rb+ty4+u)*512 + base+tx4+v] = acc2[u][v];
  }

  // ---- diag panel b: gram, factor, invert
  {
    float acc[4][4] = {{0.f}};
    for (int kc = 0; kc < Rb; kc += 16) {
      float4 ca = *(const float4*)(A + (Rb+lrow)*512 + kc + lc4);
      LkC[lrow][lc4+0]=ca.x; LkC[lrow][lc4+1]=ca.y; LkC[lrow][lc4+2]=ca.z; LkC[lrow][lc4+3]=ca.w;
      __syncthreads();
      #pragma unroll
      for (int kk = 0; kk < 16; ++kk) {
        float a0=LkC[ty4+0][kk],a1=LkC[ty4+1][kk],a2=LkC[ty4+2][kk],a3=LkC[ty4+3][kk];
        float b0=LkC[tx4+0][kk],b1=LkC[tx4+1][kk],b2=LkC[tx4+2][kk],b3=LkC[tx4+3][kk];
        FMA16(acc,a0,a1,a2,a3,b0,b1,b2,b3)
      }
      __syncthreads();
    }
    #pragma unroll
    for (int u = 0; u < 4; ++u)
      #pragma unroll
      for (int v = 0; v < 4; ++v)
        Ds[ty4+u][tx4+v] = A[(Rb+ty4+u)*512 + Rb+tx4+v] - acc[u][v];
    __syncthreads();
    // in-LDS right-looking Cholesky of 64x64
    for (int j = 0; j < 64; ++j) {
      float s = Ds[j][j];
      float Ljj = sqrtf(s);
      float rinv = 1.0f/Ljj;
      __syncthreads();
      if (tid == 0) Ds[j][j] = Ljj;
      if (tid > j && tid < 64) Ds[tid][j] *= rinv;
      __syncthreads();
      int i = tid >> 2, ko = tid & 3;
      if (i > j) {
        float lij = Ds[i][j];
        for (int k = j+1+ko; k <= i; k += 4) Ds[i][k] -= lij*Ds[k][j];
      }
      __syncthreads();
    }
    // in-LDS inverse of the lower-tri factor
    for (int e = tid; e < 4096; e += 256) Vs[e>>6][e&63] = 0.0f;
    __syncthreads();
    int c = tid & 63, q = tid >> 6;
    for (int j = 0; j < 64; ++j) {
      float partial = 0.f;
      if (j > c) for (int k = c+q; k < j; k += 4) partial += Ds[j][k]*Vs[k][c];
      red[c][q] = partial;
      __syncthreads();
      if (q == 0 && j >= c) {
        float sum = red[c][0]+red[c][1]+red[c][2]+red[c][3];
        Vs[j][c] = (((j==c)?1.0f:0.0f) - sum) / Ds[j][j];
      }
      __syncthreads();
    }
    for (int e = tid; e < 4096; e += 256) {
      int i = e >> 6, jj = e & 63;
      if (jj <= i) A[(Rb+i)*512 + Rb + jj] = Ds[i][jj];
      DINV[b*4096 + e] = Vs[i][jj];
    }
    raise_flag(&flg[b], tid);
  }
}

// ------------- Linv tiles (stored transposed as LT), per-tile flags
__global__ __launch_bounds__(256) void k_linv(float* __restrict__ ws) {
  float* A = ws + OFF_A;
  float* LT = ws + OFF_LINV;
  float* DINV = ws + OFF_DINV;
  unsigned* flg = (unsigned*)(ws + OFF_FLAGS) + 8;
  int tid = threadIdx.x;
  int s = blockIdx.x >> 3, J = blockIdx.x & 7;
  if (s < J) {  // upper of Linv is zero -> LT rows 64J.., cols 64s..
    for (int e = tid; e < 4096; e += 256)
      LT[(64*J + (e>>6))*512 + 64*s + (e&63)] = 0.0f;
    return;
  }
  if (s == J) { // Linv[s][s] = Dinv_s ; store transposed
    for (int e = tid; e < 4096; e += 256) {
      int i = e >> 6, j = e & 63;
      LT[(64*s+j)*512 + 64*s + i] = DINV[s*4096 + e];
    }
    raise_flag(&flg[s*8+J], tid);
    return;
  }
  __shared__ float Ls[64][65];
  __shared__ float Vs[64][65];
  __shared__ float T[64][65];
  __shared__ float Dv[64][65];
  int ty4 = (tid >> 4)*4, tx4 = (tid & 15)*4;
  float acc[4][4] = {{0.f}};
  for (int k = J; k < s; ++k) {
    wait_flag(&flg[k*8+J], tid);
    for (int e = tid; e < 1024; e += 256) {
      int row = e >> 4, m4 = (e & 15)*4;
      float4 a = *(const float4*)(A + (64*s+row)*512 + 64*k + m4);
      Ls[row][m4+0]=a.x; Ls[row][m4+1]=a.y; Ls[row][m4+2]=a.z; Ls[row][m4+3]=a.w;
      float4 v = *(const float4*)(LT + (64*J+row)*512 + 64*k + m4);
      Vs[m4+0][row]=v.x; Vs[m4+1][row]=v.y; Vs[m4+2][row]=v.z; Vs[m4+3][row]=v.w;
    }
    __syncthreads();
    for (int m = 0; m < 64; ++m) {
      float a0=Ls[ty4+0][m],a1=Ls[ty4+1][m],a2=Ls[ty4+2][m],a3=Ls[ty4+3][m];
      float b0=Vs[m][tx4+0],b1=Vs[m][tx4+1],b2=Vs[m][tx4+2],b3=Vs[m][tx4+3];
      FMA16(acc,a0,a1,a2,a3,b0,b1,b2,b3)
    }
    __syncthreads();
  }
  #pragma unroll
  for (int u = 0; u < 4; ++u)
    #pragma unroll
    for (int v = 0; v < 4; ++v)
      T[ty4+u][tx4+v] = acc[u][v];
  for (int e = tid; e < 4096; e += 256) Dv[e>>6][e&63] = DINV[s*4096 + e];
  __syncthreads();
  float acc2[4][4] = {{0.f}};
  for (int m = 0; m < 64; ++m) {
    float a0=Dv[ty4+0][m],a1=Dv[ty4+1][m],a2=Dv[ty4+2][m],a3=Dv[ty4+3][m];
    float b0=T[m][tx4+0],b1=T[m][tx4+1],b2=T[m][tx4+2],b3=T[m][tx4+3];
    FMA16(acc2,a0,a1,a2,a3,b0,b1,b2,b3)
  }
  #pragma unroll
  for (int u = 0; u < 4; ++u)
    #pragma unroll
    for (int v = 0; v < 4; ++v)
      LT[(64*J+tx4+v)*512 + 64*s+ty4+u] = -acc2[u][v];
  raise_flag(&flg[s*8+J], tid);
}

// --------------------- w = Linv^T q_mu  (w[c] = sum_r LT[c][r] qmu[r])
__global__ __launch_bounds__(256) void k_wvec(const float* __restrict__ qmu,
                                              float* __restrict__ ws) {
  const float* LT = ws + OFF_LINV;
  float* W = ws + OFF_W;
  __shared__ float part[256];
  int tid = threadIdx.x;
  int c = blockIdx.x*64 + (tid >> 2);
  int q = tid & 3;
  float acc = 0.f;
  for (int r = q*128; r < q*128 + 128; r += 4) {
    float4 v = *(const float4*)(LT + c*512 + r);
    float4 m = *(const float4*)(qmu + r);
    acc += v.x*m.x + v.y*m.y + v.z*m.z + v.w*m.w;
  }
  part[tid] = acc;
  __syncthreads();
  if (q == 0) W[c] = part[tid]+part[tid+1]+part[tid+2]+part[tid+3];
}

// --------------------- main: per-point quadratic forms + ell partials
__global__ __launch_bounds__(256) void k_main(const float* __restrict__ X,
    const float* __restrict__ Yv, const float* __restrict__ Z,
    const float* __restrict__ llvP, const float* __restrict__ lsP,
    const float* __restrict__ osP, float* __restrict__ ws) {
  const float* LT = ws + OFF_LINV;
  const float* QC = ws + OFF_QC;
  const float* W = ws + OFF_W;
  float* PART = ws + OFF_PART;
  __shared__ float KL[8192];      // [c][pt] 512 x 16 : k tile, then l tile
  __shared__ float RD[2176];      // 2 x 64x17 reduction scratch
  __shared__ float wsh[512];
  __shared__ float Xs[16][8];
  __shared__ float pmv[16], lsqv[16], elli[16];
  int tid = threadIdx.x, B = blockIdx.x;
  float ls = lsP[0], os = osP[0], llv = llvP[0];
  float ils2 = 1.0f/(ls*ls);
  if (tid < 128) { int pp = tid>>3, d = tid&7; Xs[pp][d] = X[(B*16+pp)*8 + d]; }
  wsh[tid] = W[tid]; wsh[tid+256] = W[tid+256];
  __syncthreads();
  for (int e = tid; e < 8192; e += 256) {
    int cc = e >> 4, pp = e & 15;
    float4 z0 = *(const float4*)(Z + cc*8);
    float4 z1 = *(const float4*)(Z + cc*8 + 4);
    float d0=z0.x-Xs[pp][0], d1=z0.y-Xs[pp][1], d2=z0.z-Xs[pp][2], d3=z0.w-Xs[pp][3];
    float d4=z1.x-Xs[pp][4], d5=z1.y-Xs[pp][5], d6=z1.z-Xs[pp][6], d7=z1.w-Xs[pp][7];
    float sq = d0*d0+d1*d1+d2*d2+d3*d3+d4*d4+d5*d5+d6*d6+d7*d7;
    KL[e] = os*__expf(-0.5f*ils2*sq);
  }
  __syncthreads();
  int rq = tid >> 2;
  int rq4 = rq*4, pq4 = (tid & 3)*4;
  // phase A: l[r][pt] = sum_c LT[c][r] * k[c][pt]
  float acc0[4][4] = {{0.f}}, acc1[4][4] = {{0.f}};
  #pragma unroll 4
  for (int c = 0; c < 256; ++c) {
    float4 kv = *(const float4*)&KL[c*16 + pq4];
    float4 l0 = *(const float4*)(LT + c*512 + rq4);
    float4 l1 = *(const float4*)(LT + c*512 + 256 + rq4);
    FMA16(acc0, l0.x,l0.y,l0.z,l0.w, kv.x,kv.y,kv.z,kv.w)
    FMA16(acc1, l1.x,l1.y,l1.z,l1.w, kv.x,kv.y,kv.z,kv.w)
  }
  #pragma unroll 4
  for (int c = 256; c < 512; ++c) {
    float4 kv = *(const float4*)&KL[c*16 + pq4];
    float4 l1 = *(const float4*)(LT + c*512 + 256 + rq4);
    FMA16(acc1, l1.x,l1.y,l1.z,l1.w, kv.x,kv.y,kv.z,kv.w)
  }
  // pred-mean partials (KL still holds k) and ||l||^2 partials
  float pmp[4] = {0.f,0.f,0.f,0.f};
  for (int c8 = 0; c8 < 8; ++c8) {
    int cc2 = rq*8 + c8;
    float wv = wsh[cc2];
    pmp[0] += KL[cc2*16+pq4+0]*wv; pmp[1] += KL[cc2*16+pq4+1]*wv;
    pmp[2] += KL[cc2*16+pq4+2]*wv; pmp[3] += KL[cc2*16+pq4+3]*wv;
  }
  float lsp[4] = {0.f,0.f,0.f,0.f};
  #pragma unroll
  for (int u = 0; u < 4; ++u)
    #pragma unroll
    for (int v = 0; v < 4; ++v)
      lsp[v] += acc0[u][v]*acc0[u][v] + acc1[u][v]*acc1[u][v];
  #pragma unroll
  for (int v = 0; v < 4; ++v) {
    RD[rq*17 + pq4+v] = pmp[v];
    RD[1088 + rq*17 + pq4+v] = lsp[v];
  }
  __syncthreads();
  if (tid < 16) {
    float a = 0.f, b = 0.f;
    for (int r2 = 0; r2 < 64; ++r2) { a += RD[r2*17+tid]; b += RD[1088+r2*17+tid]; }
    pmv[tid] = a; lsqv[tid] = b;
  }
  __syncthreads();
  // overwrite KL with l
  #pragma unroll
  for (int u = 0; u < 4; ++u) {
    *(float4*)&KL[(rq4+u)*16 + pq4] = make_float4(acc0[u][0],acc0[u][1],acc0[u][2],acc0[u][3]);
    *(float4*)&KL[(256+rq4+u)*16 + pq4] = make_float4(acc1[u][0],acc1[u][1],acc1[u][2],acc1[u][3]);
  }
  __syncthreads();
  // phase B: u = QC @ l (QC symmetric -> row access), accumulate ||u||^2
  float ua0[4][4] = {{0.f}}, ua1[4][4] = {{0.f}};
  #pragma unroll 4
  for (int c = 0; c < 512; ++c) {
    float4 kv = *(const float4*)&KL[c*16 + pq4];
    float4 q0 = *(const float4*)(QC + c*512 + rq4);
    float4 q1 = *(const float4*)(QC + c*512 + 256 + rq4);
    FMA16(ua0, q0.x,q0.y,q0.z,q0.w, kv.x,kv.y,kv.z,kv.w)
    FMA16(ua1, q1.x,q1.y,q1.z,q1.w, kv.x,kv.y,kv.z,kv.w)
  }
  float usq[4] = {0.f,0.f,0.f,0.f};
  #pragma unroll
  for (int u = 0; u < 4; ++u)
    #pragma unroll
    for (int v = 0; v < 4; ++v)
      usq[v] += ua0[u][v]*ua0[u][v] + ua1[u][v]*ua1[u][v];
  #pragma unroll
  for (int v = 0; v < 4; ++v) RD[rq*17 + pq4+v] = usq[v];
  __syncthreads();
  if (tid < 16) {
    float us = 0.f;
    for (int r2 = 0; r2 < 64; ++r2) us += RD[r2*17+tid];
    int gi = B*16 + tid;
    float diff = Yv[gi] - pmv[tid];
    float diagc = os + us - lsqv[tid];
    float iss = __expf(-llv);
    elli[tid] = -0.5f*((diff*diff + diagc)*iss + (LOG2PI + llv));
  }
  __syncthreads();
  if (tid == 0) {
    float s = 0.f;
    #pragma unroll
    for (int i2 = 0; i2 < 16; ++i2) s += elli[i2];
    PART[B] = s;
  }
}

// --------------------- final scalar
__global__ __launch_bounds__(256) void k_final(const float* __restrict__ qmu,
    const float* __restrict__ qlv, float* __restrict__ ws, float* __restrict__ out) {
  __shared__ double sh[256];
  int tid = threadIdx.x;
  const float* QC = ws + OFF_QC;
  const float* PART = ws + OFF_PART;
  double pa = 0.0, tr = 0.0, mm = 0.0, ld = 0.0;
  for (int i = tid; i < 512; i += 256) {
    pa += (double)PART[i];
    tr += (double)QC[i*513];
    double q = (double)qmu[i]; mm += q*q;
    ld += (double)qlv[i*513];
  }
  double vals[4] = {pa, tr, mm, ld};
  double res[4];
  for (int t2 = 0; t2 < 4; ++t2) {
    sh[tid] = vals[t2]; __syncthreads();
    for (int s2 = 128; s2 > 0; s2 >>= 1) {
      if (tid < s2) sh[tid] += sh[tid+s2];
      __syncthreads();
    }
    res[t2] = sh[0]; __syncthreads();
  }
  if (tid == 0) {
    double n = 8192.0;
    double ell = res[0]/n;
    double kl = 0.5*(res[1] + res[2] - 512.0 - res[3])/n;
    out[0] = (float)(ell - kl);
  }
}

extern "C" void kernel_launch(void* const* d_in, const int* in_sizes, int n_in,
                              void* d_out, int out_size, void* d_ws, size_t ws_size,
                              hipStream_t stream) {
  (void)in_sizes; (void)n_in; (void)out_size; (void)ws_size;
  const float* X   = (const float*)d_in[0];
  const float* Y   = (const float*)d_in[1];
  const float* Z   = (const float*)d_in[2];
  const float* qmu = (const float*)d_in[3];
  const float* qlv = (const float*)d_in[4];
  const float* llv = (const float*)d_in[5];
  const float* ls  = (const float*)d_in[6];
  const float* os  = (const float*)d_in[7];
  float* ws = (float*)d_ws;
  float* out = (float*)d_out;

  k_prep<<<2048, 256, 0, stream>>>(Z, qlv, ls, os, ws);
  k_gemm_nt<<<dim3(8,8), 256, 0, stream>>>(ws+OFF_QS, ws+OFF_QS, ws+OFF_QC, JIT);
  k_chol_all<<<8, 256, 0, stream>>>(ws);
  k_linv<<<64, 256, 0, stream>>>(ws);
  k_wvec<<<8, 256, 0, stream>>>(qmu, ws);
  k_main<<<512, 256, 0, stream>>>(X, Y, Z, llv, ls, os, ws);
  k_final<<<1, 256, 0, stream>>>(qmu, qlv, ws, out);
}